// Round 1
// baseline (659.690 us; speedup 1.0000x reference)
//
#include <hip/hip_runtime.h>
#include <cstdint>

using u16 = unsigned short;
using u32 = unsigned int;
typedef __attribute__((ext_vector_type(8))) short short8;
typedef __attribute__((ext_vector_type(4))) float f32x4;

__device__ __forceinline__ float bf2f(u16 u) { return __uint_as_float(((u32)u) << 16); }
__device__ __forceinline__ u16 f2bf(float f) {
    u32 u = __float_as_uint(f);
    u32 r = u + 0x7fffu + ((u >> 16) & 1u);   // round-to-nearest-even
    return (u16)(r >> 16);
}

__device__ __forceinline__ void load_lds16(const void* g, void* l) {
    __builtin_amdgcn_global_load_lds((const __attribute__((address_space(1))) void*)g,
                                     (__attribute__((address_space(3))) void*)l, 16, 0, 0);
}

// ---------------- LayerNorm(row of 1024 fp32) -> bf16 ----------------
__global__ __launch_bounds__(256)
void ln_cast_kernel(const float* __restrict__ x, const float* __restrict__ gw,
                    const float* __restrict__ bw, u16* __restrict__ y) {
    const int row = blockIdx.x;
    const int tid = threadIdx.x;
    const float4 v = ((const float4*)(x + (size_t)row * 1024))[tid];
    float s  = v.x + v.y + v.z + v.w;
    float ss = v.x * v.x + v.y * v.y + v.z * v.z + v.w * v.w;
#pragma unroll
    for (int off = 32; off; off >>= 1) {
        s  += __shfl_xor(s, off);
        ss += __shfl_xor(ss, off);
    }
    __shared__ float sm[8];
    const int lane = tid & 63, wid = tid >> 6;
    if (lane == 0) { sm[wid] = s; sm[wid + 4] = ss; }
    __syncthreads();
    s  = sm[0] + sm[1] + sm[2] + sm[3];
    ss = sm[4] + sm[5] + sm[6] + sm[7];
    const float mu   = s * (1.0f / 1024.0f);
    const float var  = ss * (1.0f / 1024.0f) - mu * mu;
    const float rstd = rsqrtf(var + 1e-5f);
    const float4 g4 = ((const float4*)gw)[tid];
    const float4 b4 = ((const float4*)bw)[tid];
    u16 o[4];
    o[0] = f2bf((v.x - mu) * rstd * g4.x + b4.x);
    o[1] = f2bf((v.y - mu) * rstd * g4.y + b4.y);
    o[2] = f2bf((v.z - mu) * rstd * g4.z + b4.z);
    o[3] = f2bf((v.w - mu) * rstd * g4.w + b4.w);
    *(uint2*)(y + (size_t)row * 1024 + tid * 4) = *(uint2*)o;
}

// ---------------- fp32 -> bf16 cast (weights) ----------------
__global__ __launch_bounds__(256)
void cast_kernel(const float* __restrict__ x, u16* __restrict__ y) {
    const int i = blockIdx.x * 256 + threadIdx.x;
    const float4 v = ((const float4*)x)[i];
    u16 o[4] = { f2bf(v.x), f2bf(v.y), f2bf(v.z), f2bf(v.w) };
    *(uint2*)(y + (size_t)i * 4) = *(uint2*)o;
}

// ---------------- GEMM  C = A(MxK) * B(NxK)^T  (both K-contiguous, bf16 in) -----
// MODE 0: bf16 out row-major, +bias      (Q/K projection)
// MODE 1: bf16 out transposed per batch, +bias  (V projection -> vT[b][n][m%2048])
// MODE 2: bf16 out row-major per batch, *scale  (dots/logits)
// MODE 3: fp32 out row-major per batch          (PV -> final output)
template<int MODE>
__global__ __launch_bounds__(256)
void gemm_bt(const u16* __restrict__ A, const u16* __restrict__ B,
             const float* __restrict__ bias, void* __restrict__ Cout,
             const int M, const int N, const int K, const float scale,
             const long sA, const long sB, const long sC)
{
    const int bz = blockIdx.z;
    A += (long)bz * sA;
    B += (long)bz * sB;
    __shared__ __align__(16) u16 As[128 * 32];
    __shared__ __align__(16) u16 Bs[128 * 32];
    const int tid  = threadIdx.x;
    const int lane = tid & 63, wid = tid >> 6;
    const int wm = (wid & 1) * 64, wn = (wid >> 1) * 64;
    const int m0 = blockIdx.x * 128, n0 = blockIdx.y * 128;

    // staging: thread t loads 16B from row t/4, col-block (t&3)*8 (2 row-rounds of 64)
    const u16* ap = A + (long)(m0 + (tid >> 2)) * K + (tid & 3) * 8;
    const u16* bp = B + (long)(n0 + (tid >> 2)) * K + (tid & 3) * 8;
    u16* asd = As + wid * 512;
    u16* bsd = Bs + wid * 512;
    const long rowskip = 64L * K;

    f32x4 acc[4][4] = {};
    const int fr = lane & 15, fq = lane >> 4;

    for (int k0 = 0; k0 < K; k0 += 32) {
        load_lds16(ap + k0,            asd);
        load_lds16(ap + rowskip + k0,  asd + 2048);
        load_lds16(bp + k0,            bsd);
        load_lds16(bp + rowskip + k0,  bsd + 2048);
        __syncthreads();
        short8 af[4], bfv[4];
#pragma unroll
        for (int i = 0; i < 4; i++)
            af[i] = *(const short8*)&As[(wm + i * 16 + fr) * 32 + fq * 8];
#pragma unroll
        for (int j = 0; j < 4; j++)
            bfv[j] = *(const short8*)&Bs[(wn + j * 16 + fr) * 32 + fq * 8];
#pragma unroll
        for (int i = 0; i < 4; i++)
#pragma unroll
            for (int j = 0; j < 4; j++)
                acc[i][j] = __builtin_amdgcn_mfma_f32_16x16x32_bf16(af[i], bfv[j], acc[i][j], 0, 0, 0);
        __syncthreads();
    }

    // epilogue: C/D layout col=lane&15, row=(lane>>4)*4+r
    const int cn = lane & 15;
    const int cm = (lane >> 4) * 4;
#pragma unroll
    for (int i = 0; i < 4; i++) {
        const int gmb = m0 + wm + i * 16 + cm;
#pragma unroll
        for (int j = 0; j < 4; j++) {
            const int gn = n0 + wn + j * 16 + cn;
            const float bv = (MODE <= 1) ? bias[gn] : 0.0f;
            if (MODE == 1) {
                const int batch = gmb >> 11;
                const int jj = gmb & 2047;
                u16 o[4];
#pragma unroll
                for (int r = 0; r < 4; r++) o[r] = f2bf(acc[i][j][r] + bv);
                *(uint2*)((u16*)Cout + ((long)batch * N + gn) * 2048 + jj) = *(uint2*)o;
            } else {
#pragma unroll
                for (int r = 0; r < 4; r++) {
                    const long gm = gmb + r;
                    float v = acc[i][j][r];
                    if (MODE == 0) v += bv;
                    if (MODE == 2) v *= scale;
                    if (MODE == 3)
                        ((float*)Cout)[(long)bz * sC + gm * N + gn] = v;
                    else if (MODE == 2)
                        ((u16*)Cout)[(long)bz * sC + gm * N + gn] = f2bf(v);
                    else
                        ((u16*)Cout)[gm * (long)N + gn] = f2bf(v);
                }
            }
        }
    }
}

// ---------------- in-place row softmax on bf16 rows of 2048 ----------------
__global__ __launch_bounds__(256)
void softmax_kernel(u16* __restrict__ S) {
    const size_t row = blockIdx.x;
    u16* r = S + row * 2048;
    const int tid = threadIdx.x;
    const uint4 raw = *(const uint4*)(r + tid * 8);
    float v[8];
    v[0] = bf2f((u16)(raw.x & 0xffffu)); v[1] = bf2f((u16)(raw.x >> 16));
    v[2] = bf2f((u16)(raw.y & 0xffffu)); v[3] = bf2f((u16)(raw.y >> 16));
    v[4] = bf2f((u16)(raw.z & 0xffffu)); v[5] = bf2f((u16)(raw.z >> 16));
    v[6] = bf2f((u16)(raw.w & 0xffffu)); v[7] = bf2f((u16)(raw.w >> 16));
    float mx = v[0];
#pragma unroll
    for (int i = 1; i < 8; i++) mx = fmaxf(mx, v[i]);
#pragma unroll
    for (int off = 32; off; off >>= 1) mx = fmaxf(mx, __shfl_xor(mx, off));
    __shared__ float sm[4];
    __shared__ float sm2[4];
    const int lane = tid & 63, wid = tid >> 6;
    if (lane == 0) sm[wid] = mx;
    __syncthreads();
    mx = fmaxf(fmaxf(sm[0], sm[1]), fmaxf(sm[2], sm[3]));
    float s = 0.f;
#pragma unroll
    for (int i = 0; i < 8; i++) { v[i] = __expf(v[i] - mx); s += v[i]; }
#pragma unroll
    for (int off = 32; off; off >>= 1) s += __shfl_xor(s, off);
    if (lane == 0) sm2[wid] = s;
    __syncthreads();
    s = sm2[0] + sm2[1] + sm2[2] + sm2[3];
    const float inv = 1.0f / s;
    u16 o[8];
#pragma unroll
    for (int i = 0; i < 8; i++) o[i] = f2bf(v[i] * inv);
    *(uint4*)(r + tid * 8) = *(uint4*)o;
}

extern "C" void kernel_launch(void* const* d_in, const int* in_sizes, int n_in,
                              void* d_out, int out_size, void* d_ws, size_t ws_size,
                              hipStream_t stream) {
    const float* target = (const float*)d_in[0];
    const float* src_k  = (const float*)d_in[1];
    const float* src_v  = (const float*)d_in[2];
    const float* Wq = (const float*)d_in[3];
    const float* bq = (const float*)d_in[4];
    const float* Wk = (const float*)d_in[5];
    const float* bk = (const float*)d_in[6];
    const float* Wv = (const float*)d_in[7];
    const float* bv = (const float*)d_in[8];
    const float* g_t = (const float*)d_in[9];
    const float* b_t = (const float*)d_in[10];
    const float* g_k = (const float*)d_in[11];
    const float* b_k = (const float*)d_in[12];
    const float* g_v = (const float*)d_in[13];
    const float* b_v = (const float*)d_in[14];

    // workspace layout (bytes); peak use ~160 MiB
    char* ws = (char*)d_ws;
    u16* q   = (u16*)(ws + 0);            // 16384x1024 bf16  (33.5 MB)
    u16* kk  = (u16*)(ws + 33554432L);    // 16384x1024 bf16
    u16* vT  = (u16*)(ws + 67108864L);    // 8 x 1024 x 2048 bf16
    u16* ln  = (u16*)(ws + 100663296L);   // 16384x1024 bf16 (reused 3x)
    u16* wqb = (u16*)(ws + 134217728L);   // 3 x 1024x1024 bf16
    u16* wkb = wqb + 1048576;
    u16* wvb = wkb + 1048576;
    u16* S   = (u16*)(ws + 100663296L);   // 8x2048x2048 bf16 (aliases ln+W, both dead)

    const float scale = 0.03125f;  // 1024^-0.5

    cast_kernel<<<1024, 256, 0, stream>>>(Wq, wqb);
    cast_kernel<<<1024, 256, 0, stream>>>(Wk, wkb);
    cast_kernel<<<1024, 256, 0, stream>>>(Wv, wvb);

    // Q = LN(target) @ Wq^T + bq
    ln_cast_kernel<<<16384, 256, 0, stream>>>(target, g_t, b_t, ln);
    gemm_bt<0><<<dim3(128, 8, 1), 256, 0, stream>>>(ln, wqb, bq, q,
        16384, 1024, 1024, 1.0f, 0, 0, 0);
    // K = LN(source_k) @ Wk^T + bk
    ln_cast_kernel<<<16384, 256, 0, stream>>>(src_k, g_k, b_k, ln);
    gemm_bt<0><<<dim3(128, 8, 1), 256, 0, stream>>>(ln, wkb, bk, kk,
        16384, 1024, 1024, 1.0f, 0, 0, 0);
    // V = LN(source_v) @ Wv^T + bv, stored transposed per batch: vT[b][d][j]
    ln_cast_kernel<<<16384, 256, 0, stream>>>(src_v, g_v, b_v, ln);
    gemm_bt<1><<<dim3(128, 8, 1), 256, 0, stream>>>(ln, wvb, bv, vT,
        16384, 1024, 1024, 1.0f, 0, 0, 0);

    // S[b] = (q[b] @ k[b]^T) * scale   -> bf16 logits
    gemm_bt<2><<<dim3(16, 16, 8), 256, 0, stream>>>(q, kk, nullptr, S,
        2048, 2048, 1024, scale, 2048L * 1024, 2048L * 1024, 2048L * 2048);

    // softmax rows in-place
    softmax_kernel<<<16384, 256, 0, stream>>>(S);

    // out[b] = P[b] @ vT[b]^T  -> fp32
    gemm_bt<3><<<dim3(16, 8, 8), 256, 0, stream>>>(S, vT, nullptr, d_out,
        2048, 1024, 2048, 1.0f, 2048L * 2048, 1024L * 2048, 2048L * 1024);
}

// Round 2
// 645.689 us; speedup vs baseline: 1.0217x; 1.0217x over previous
//
#include <hip/hip_runtime.h>
#include <cstdint>

using u16 = unsigned short;
using u32 = unsigned int;
typedef __attribute__((ext_vector_type(8))) short short8;
typedef __attribute__((ext_vector_type(4))) float f32x4;

__device__ __forceinline__ float bf2f(u16 u) { return __uint_as_float(((u32)u) << 16); }
__device__ __forceinline__ u16 f2bf(float f) {
    u32 u = __float_as_uint(f);
    u32 r = u + 0x7fffu + ((u >> 16) & 1u);   // round-to-nearest-even
    return (u16)(r >> 16);
}

__device__ __forceinline__ void load_lds16(const void* g, void* l) {
    __builtin_amdgcn_global_load_lds((const __attribute__((address_space(1))) void*)g,
                                     (__attribute__((address_space(3))) void*)l, 16, 0, 0);
}

// ---------------- LayerNorm(row of 1024 fp32) -> bf16 ----------------
__global__ __launch_bounds__(256)
void ln_cast_kernel(const float* __restrict__ x, const float* __restrict__ gw,
                    const float* __restrict__ bw, u16* __restrict__ y) {
    const int row = blockIdx.x;
    const int tid = threadIdx.x;
    const float4 v = ((const float4*)(x + (size_t)row * 1024))[tid];
    float s  = v.x + v.y + v.z + v.w;
    float ss = v.x * v.x + v.y * v.y + v.z * v.z + v.w * v.w;
#pragma unroll
    for (int off = 32; off; off >>= 1) {
        s  += __shfl_xor(s, off);
        ss += __shfl_xor(ss, off);
    }
    __shared__ float sm[8];
    const int lane = tid & 63, wid = tid >> 6;
    if (lane == 0) { sm[wid] = s; sm[wid + 4] = ss; }
    __syncthreads();
    s  = sm[0] + sm[1] + sm[2] + sm[3];
    ss = sm[4] + sm[5] + sm[6] + sm[7];
    const float mu   = s * (1.0f / 1024.0f);
    const float var  = ss * (1.0f / 1024.0f) - mu * mu;
    const float rstd = rsqrtf(var + 1e-5f);
    const float4 g4 = ((const float4*)gw)[tid];
    const float4 b4 = ((const float4*)bw)[tid];
    u16 o[4];
    o[0] = f2bf((v.x - mu) * rstd * g4.x + b4.x);
    o[1] = f2bf((v.y - mu) * rstd * g4.y + b4.y);
    o[2] = f2bf((v.z - mu) * rstd * g4.z + b4.z);
    o[3] = f2bf((v.w - mu) * rstd * g4.w + b4.w);
    *(uint2*)(y + (size_t)row * 1024 + tid * 4) = *(uint2*)o;
}

// ---------------- fp32 -> bf16 cast (weights) ----------------
__global__ __launch_bounds__(256)
void cast_kernel(const float* __restrict__ x, u16* __restrict__ y) {
    const int i = blockIdx.x * 256 + threadIdx.x;
    const float4 v = ((const float4*)x)[i];
    u16 o[4] = { f2bf(v.x), f2bf(v.y), f2bf(v.z), f2bf(v.w) };
    *(uint2*)(y + (size_t)i * 4) = *(uint2*)o;
}

// ---------------- GEMM  C = A(MxK) * B(NxK)^T  (both K-contiguous, bf16 in) -----
// LDS layout is K-group XOR-swizzled: slot (r, c') holds global (r, c'^((r>>1)&3)).
// Implemented on the staging side by permuting which global col each lane fetches
// (global_load_lds dest is fixed at base+lane*16), and on the read side by the
// same XOR. Kills the 8-way ds_read_b128 bank conflict of the naive layout.
// MODE 0: bf16 out row-major, +bias      (Q/K projection)
// MODE 1: bf16 out transposed per batch, +bias  (V projection -> vT[b][n][m%2048])
// MODE 2: bf16 out row-major per batch, *scale  (dots/logits)
// MODE 3: fp32 out row-major per batch          (PV -> final output)
template<int MODE>
__global__ __launch_bounds__(256)
void gemm_bt(const u16* __restrict__ A, const u16* __restrict__ B,
             const float* __restrict__ bias, void* __restrict__ Cout,
             const int M, const int N, const int K, const float scale,
             const long sA, const long sB, const long sC)
{
    const int bz = blockIdx.z;
    A += (long)bz * sA;
    B += (long)bz * sB;
    __shared__ __align__(16) u16 As[128 * 32];
    __shared__ __align__(16) u16 Bs[128 * 32];
    const int tid  = threadIdx.x;
    const int lane = tid & 63, wid = tid >> 6;
    const int wm = (wid & 1) * 64, wn = (wid >> 1) * 64;
    const int m0 = blockIdx.x * 128, n0 = blockIdx.y * 128;

    // staging: thread t covers row t>>2, swizzled col-group (t&3)^((t>>3)&3)
    const int scol = ((tid & 3) ^ ((tid >> 3) & 3));
    const u16* ap = A + (long)(m0 + (tid >> 2)) * K + scol * 8;
    const u16* bp = B + (long)(n0 + (tid >> 2)) * K + scol * 8;
    u16* asd = As + wid * 512;
    u16* bsd = Bs + wid * 512;
    const long rowskip = 64L * K;

    f32x4 acc[4][4] = {};
    const int fr = lane & 15, fq = lane >> 4;
    const int cg = (fq ^ ((fr >> 1) & 3)) * 8;   // swizzled k-group for frag reads

    for (int k0 = 0; k0 < K; k0 += 32) {
        load_lds16(ap + k0,            asd);
        load_lds16(ap + rowskip + k0,  asd + 2048);
        load_lds16(bp + k0,            bsd);
        load_lds16(bp + rowskip + k0,  bsd + 2048);
        __syncthreads();
        short8 af[4], bfv[4];
#pragma unroll
        for (int i = 0; i < 4; i++)
            af[i] = *(const short8*)&As[(wm + i * 16 + fr) * 32 + cg];
#pragma unroll
        for (int j = 0; j < 4; j++)
            bfv[j] = *(const short8*)&Bs[(wn + j * 16 + fr) * 32 + cg];
#pragma unroll
        for (int i = 0; i < 4; i++)
#pragma unroll
            for (int j = 0; j < 4; j++)
                acc[i][j] = __builtin_amdgcn_mfma_f32_16x16x32_bf16(af[i], bfv[j], acc[i][j], 0, 0, 0);
        __syncthreads();
    }

    // epilogue: C/D layout col=lane&15, row=(lane>>4)*4+r
    const int cn = lane & 15;
    const int cm = (lane >> 4) * 4;
#pragma unroll
    for (int i = 0; i < 4; i++) {
        const int gmb = m0 + wm + i * 16 + cm;
#pragma unroll
        for (int j = 0; j < 4; j++) {
            const int gn = n0 + wn + j * 16 + cn;
            const float bv = (MODE <= 1) ? bias[gn] : 0.0f;
            if (MODE == 1) {
                const int batch = gmb >> 11;
                const int jj = gmb & 2047;
                u16 o[4];
#pragma unroll
                for (int r = 0; r < 4; r++) o[r] = f2bf(acc[i][j][r] + bv);
                *(uint2*)((u16*)Cout + ((long)batch * N + gn) * 2048 + jj) = *(uint2*)o;
            } else {
#pragma unroll
                for (int r = 0; r < 4; r++) {
                    const long gm = gmb + r;
                    float v = acc[i][j][r];
                    if (MODE == 0) v += bv;
                    if (MODE == 2) v *= scale;
                    if (MODE == 3)
                        ((float*)Cout)[(long)bz * sC + gm * N + gn] = v;
                    else if (MODE == 2)
                        ((u16*)Cout)[(long)bz * sC + gm * N + gn] = f2bf(v);
                    else
                        ((u16*)Cout)[gm * (long)N + gn] = f2bf(v);
                }
            }
        }
    }
}

// ---------------- in-place row softmax on bf16 rows of 2048 ----------------
__global__ __launch_bounds__(256)
void softmax_kernel(u16* __restrict__ S) {
    const size_t row = blockIdx.x;
    u16* r = S + row * 2048;
    const int tid = threadIdx.x;
    const uint4 raw = *(const uint4*)(r + tid * 8);
    float v[8];
    v[0] = bf2f((u16)(raw.x & 0xffffu)); v[1] = bf2f((u16)(raw.x >> 16));
    v[2] = bf2f((u16)(raw.y & 0xffffu)); v[3] = bf2f((u16)(raw.y >> 16));
    v[4] = bf2f((u16)(raw.z & 0xffffu)); v[5] = bf2f((u16)(raw.z >> 16));
    v[6] = bf2f((u16)(raw.w & 0xffffu)); v[7] = bf2f((u16)(raw.w >> 16));
    float mx = v[0];
#pragma unroll
    for (int i = 1; i < 8; i++) mx = fmaxf(mx, v[i]);
#pragma unroll
    for (int off = 32; off; off >>= 1) mx = fmaxf(mx, __shfl_xor(mx, off));
    __shared__ float sm[4];
    __shared__ float sm2[4];
    const int lane = tid & 63, wid = tid >> 6;
    if (lane == 0) sm[wid] = mx;
    __syncthreads();
    mx = fmaxf(fmaxf(sm[0], sm[1]), fmaxf(sm[2], sm[3]));
    float s = 0.f;
#pragma unroll
    for (int i = 0; i < 8; i++) { v[i] = __expf(v[i] - mx); s += v[i]; }
#pragma unroll
    for (int off = 32; off; off >>= 1) s += __shfl_xor(s, off);
    if (lane == 0) sm2[wid] = s;
    __syncthreads();
    s = sm2[0] + sm2[1] + sm2[2] + sm2[3];
    const float inv = 1.0f / s;
    u16 o[8];
#pragma unroll
    for (int i = 0; i < 8; i++) o[i] = f2bf(v[i] * inv);
    *(uint4*)(r + tid * 8) = *(uint4*)o;
}

extern "C" void kernel_launch(void* const* d_in, const int* in_sizes, int n_in,
                              void* d_out, int out_size, void* d_ws, size_t ws_size,
                              hipStream_t stream) {
    const float* target = (const float*)d_in[0];
    const float* src_k  = (const float*)d_in[1];
    const float* src_v  = (const float*)d_in[2];
    const float* Wq = (const float*)d_in[3];
    const float* bq = (const float*)d_in[4];
    const float* Wk = (const float*)d_in[5];
    const float* bk = (const float*)d_in[6];
    const float* Wv = (const float*)d_in[7];
    const float* bv = (const float*)d_in[8];
    const float* g_t = (const float*)d_in[9];
    const float* b_t = (const float*)d_in[10];
    const float* g_k = (const float*)d_in[11];
    const float* b_k = (const float*)d_in[12];
    const float* g_v = (const float*)d_in[13];
    const float* b_v = (const float*)d_in[14];

    // workspace layout (bytes); peak use ~160 MiB
    char* ws = (char*)d_ws;
    u16* q   = (u16*)(ws + 0);            // 16384x1024 bf16  (33.5 MB)
    u16* kk  = (u16*)(ws + 33554432L);    // 16384x1024 bf16
    u16* vT  = (u16*)(ws + 67108864L);    // 8 x 1024 x 2048 bf16
    u16* ln  = (u16*)(ws + 100663296L);   // 16384x1024 bf16 (reused 3x)
    u16* wqb = (u16*)(ws + 134217728L);   // 3 x 1024x1024 bf16
    u16* wkb = wqb + 1048576;
    u16* wvb = wkb + 1048576;
    u16* S   = (u16*)(ws + 100663296L);   // 8x2048x2048 bf16 (aliases ln+W, both dead)

    const float scale = 0.03125f;  // 1024^-0.5

    cast_kernel<<<1024, 256, 0, stream>>>(Wq, wqb);
    cast_kernel<<<1024, 256, 0, stream>>>(Wk, wkb);
    cast_kernel<<<1024, 256, 0, stream>>>(Wv, wvb);

    // Q = LN(target) @ Wq^T + bq
    ln_cast_kernel<<<16384, 256, 0, stream>>>(target, g_t, b_t, ln);
    gemm_bt<0><<<dim3(128, 8, 1), 256, 0, stream>>>(ln, wqb, bq, q,
        16384, 1024, 1024, 1.0f, 0, 0, 0);
    // K = LN(source_k) @ Wk^T + bk
    ln_cast_kernel<<<16384, 256, 0, stream>>>(src_k, g_k, b_k, ln);
    gemm_bt<0><<<dim3(128, 8, 1), 256, 0, stream>>>(ln, wkb, bk, kk,
        16384, 1024, 1024, 1.0f, 0, 0, 0);
    // V = LN(source_v) @ Wv^T + bv, stored transposed per batch: vT[b][d][j]
    ln_cast_kernel<<<16384, 256, 0, stream>>>(src_v, g_v, b_v, ln);
    gemm_bt<1><<<dim3(128, 8, 1), 256, 0, stream>>>(ln, wvb, bv, vT,
        16384, 1024, 1024, 1.0f, 0, 0, 0);

    // S[b] = (q[b] @ k[b]^T) * scale   -> bf16 logits
    gemm_bt<2><<<dim3(16, 16, 8), 256, 0, stream>>>(q, kk, nullptr, S,
        2048, 2048, 1024, scale, 2048L * 1024, 2048L * 1024, 2048L * 2048);

    // softmax rows in-place
    softmax_kernel<<<16384, 256, 0, stream>>>(S);

    // out[b] = P[b] @ vT[b]^T  -> fp32
    gemm_bt<3><<<dim3(16, 8, 8), 256, 0, stream>>>(S, vT, nullptr, d_out,
        2048, 1024, 2048, 1.0f, 2048L * 2048, 1024L * 2048, 2048L * 1024);
}

// Round 3
// 602.899 us; speedup vs baseline: 1.0942x; 1.0710x over previous
//
#include <hip/hip_runtime.h>
#include <cstdint>

using u16 = unsigned short;
using u32 = unsigned int;
typedef __attribute__((ext_vector_type(8))) short short8;
typedef __attribute__((ext_vector_type(4))) float f32x4;

__device__ __forceinline__ float bf2f(u16 u) { return __uint_as_float(((u32)u) << 16); }
__device__ __forceinline__ u16 f2bf(float f) {
    u32 u = __float_as_uint(f);
    u32 r = u + 0x7fffu + ((u >> 16) & 1u);   // round-to-nearest-even
    return (u16)(r >> 16);
}

__device__ __forceinline__ void load_lds16(const void* g, void* l) {
    __builtin_amdgcn_global_load_lds((const __attribute__((address_space(1))) void*)g,
                                     (__attribute__((address_space(3))) void*)l, 16, 0, 0);
}

// ---------------- LayerNorm(row of 1024 fp32) -> bf16 ----------------
__global__ __launch_bounds__(256)
void ln_cast_kernel(const float* __restrict__ x, const float* __restrict__ gw,
                    const float* __restrict__ bw, u16* __restrict__ y) {
    const int row = blockIdx.x;
    const int tid = threadIdx.x;
    const float4 v = ((const float4*)(x + (size_t)row * 1024))[tid];
    float s  = v.x + v.y + v.z + v.w;
    float ss = v.x * v.x + v.y * v.y + v.z * v.z + v.w * v.w;
#pragma unroll
    for (int off = 32; off; off >>= 1) {
        s  += __shfl_xor(s, off);
        ss += __shfl_xor(ss, off);
    }
    __shared__ float sm[8];
    const int lane = tid & 63, wid = tid >> 6;
    if (lane == 0) { sm[wid] = s; sm[wid + 4] = ss; }
    __syncthreads();
    s  = sm[0] + sm[1] + sm[2] + sm[3];
    ss = sm[4] + sm[5] + sm[6] + sm[7];
    const float mu   = s * (1.0f / 1024.0f);
    const float var  = ss * (1.0f / 1024.0f) - mu * mu;
    const float rstd = rsqrtf(var + 1e-5f);
    const float4 g4 = ((const float4*)gw)[tid];
    const float4 b4 = ((const float4*)bw)[tid];
    u16 o[4];
    o[0] = f2bf((v.x - mu) * rstd * g4.x + b4.x);
    o[1] = f2bf((v.y - mu) * rstd * g4.y + b4.y);
    o[2] = f2bf((v.z - mu) * rstd * g4.z + b4.z);
    o[3] = f2bf((v.w - mu) * rstd * g4.w + b4.w);
    *(uint2*)(y + (size_t)row * 1024 + tid * 4) = *(uint2*)o;
}

// ---------------- fp32 -> bf16 cast (weights) ----------------
__global__ __launch_bounds__(256)
void cast_kernel(const float* __restrict__ x, u16* __restrict__ y) {
    const int i = blockIdx.x * 256 + threadIdx.x;
    const float4 v = ((const float4*)x)[i];
    u16 o[4] = { f2bf(v.x), f2bf(v.y), f2bf(v.z), f2bf(v.w) };
    *(uint2*)(y + (size_t)i * 4) = *(uint2*)o;
}

// ---------------- GEMM  C = A(MxK) * B(NxK)^T  (both K-contiguous, bf16 in) -----
// BK=64, 128x128 tile. LDS slot (r, c') holds global (r, c' ^ (r&7)) [16B col
// groups]. Staging permutes WHICH global 16B chunk each lane fetches (the
// global_load_lds LDS dest is frozen at wavebase+lane*16); fragment reads
// apply the same XOR -> per 16-lane phase all 8 quad-groups x2 = conflict-free.
// MODE 0: bf16 out row-major, +bias      (Q/K projection)
// MODE 1: bf16 out transposed per batch, +bias  (V projection -> vT[b][n][m%2048])
// MODE 2: bf16 out row-major per batch, *scale  (dots/logits)
// MODE 3: fp32 out row-major per batch          (PV -> final output)
template<int MODE>
__global__ __launch_bounds__(256)
void gemm_bt(const u16* __restrict__ A, const u16* __restrict__ B,
             const float* __restrict__ bias, void* __restrict__ Cout,
             const int M, const int N, const int K, const float scale,
             const long sA, const long sB, const long sC)
{
    const int bz = blockIdx.z;
    A += (long)bz * sA;
    B += (long)bz * sB;
    __shared__ __align__(16) u16 As[128 * 64];   // 16 KB
    __shared__ __align__(16) u16 Bs[128 * 64];   // 16 KB
    const int tid  = threadIdx.x;
    const int lane = tid & 63, wid = tid >> 6;
    const int wm = (wid & 1) * 64, wn = (wid >> 1) * 64;
    const int m0 = blockIdx.x * 128, n0 = blockIdx.y * 128;

    // staging: round rd covers rows rd*32..rd*32+31; thread t -> row rd*32+(t>>3),
    // fetches global 16B col-group (t&7)^((t>>3)&7)  (swizzle)
    const int scol = (tid & 7) ^ ((tid >> 3) & 7);
    const u16* ap = A + (long)(m0 + (tid >> 3)) * K + scol * 8;
    const u16* bp = B + (long)(n0 + (tid >> 3)) * K + scol * 8;
    u16* asd = As + wid * 512;   // + rd*2048 per round; HW adds lane*16B
    u16* bsd = Bs + wid * 512;
    const long rs32 = 32L * K;

    f32x4 acc[4][4] = {};
    const int fr = lane & 15, fq = lane >> 4;

    for (int k0 = 0; k0 < K; k0 += 64) {
#pragma unroll
        for (int rd = 0; rd < 4; rd++) {
            load_lds16(ap + k0 + rd * rs32, asd + rd * 2048);
            load_lds16(bp + k0 + rd * rs32, bsd + rd * 2048);
        }
        __syncthreads();
#pragma unroll
        for (int s = 0; s < 2; s++) {
            short8 af[4], bfv[4];
#pragma unroll
            for (int i = 0; i < 4; i++) {
                const int row = wm + i * 16 + fr;
                af[i] = *(const short8*)&As[row * 64 + (((s * 4 + fq) ^ (row & 7)) * 8)];
            }
#pragma unroll
            for (int j = 0; j < 4; j++) {
                const int row = wn + j * 16 + fr;
                bfv[j] = *(const short8*)&Bs[row * 64 + (((s * 4 + fq) ^ (row & 7)) * 8)];
            }
#pragma unroll
            for (int i = 0; i < 4; i++)
#pragma unroll
                for (int j = 0; j < 4; j++)
                    acc[i][j] = __builtin_amdgcn_mfma_f32_16x16x32_bf16(af[i], bfv[j], acc[i][j], 0, 0, 0);
        }
        __syncthreads();
    }

    // epilogue: C/D layout col=lane&15, row=(lane>>4)*4+r
    const int cn = lane & 15;
    const int cm = (lane >> 4) * 4;
#pragma unroll
    for (int i = 0; i < 4; i++) {
        const int gmb = m0 + wm + i * 16 + cm;
#pragma unroll
        for (int j = 0; j < 4; j++) {
            const int gn = n0 + wn + j * 16 + cn;
            const float bv = (MODE <= 1) ? bias[gn] : 0.0f;
            if (MODE == 1) {
                const int batch = gmb >> 11;
                const int jj = gmb & 2047;
                u16 o[4];
#pragma unroll
                for (int r = 0; r < 4; r++) o[r] = f2bf(acc[i][j][r] + bv);
                *(uint2*)((u16*)Cout + ((long)batch * N + gn) * 2048 + jj) = *(uint2*)o;
            } else {
#pragma unroll
                for (int r = 0; r < 4; r++) {
                    const long gm = gmb + r;
                    float v = acc[i][j][r];
                    if (MODE == 0) v += bv;
                    if (MODE == 2) v *= scale;
                    if (MODE == 3)
                        ((float*)Cout)[(long)bz * sC + gm * N + gn] = v;
                    else if (MODE == 2)
                        ((u16*)Cout)[(long)bz * sC + gm * N + gn] = f2bf(v);
                    else
                        ((u16*)Cout)[gm * (long)N + gn] = f2bf(v);
                }
            }
        }
    }
}

// ---------------- in-place row softmax on bf16 rows of 2048 ----------------
__global__ __launch_bounds__(256)
void softmax_kernel(u16* __restrict__ S) {
    const size_t row = blockIdx.x;
    u16* r = S + row * 2048;
    const int tid = threadIdx.x;
    const uint4 raw = *(const uint4*)(r + tid * 8);
    float v[8];
    v[0] = bf2f((u16)(raw.x & 0xffffu)); v[1] = bf2f((u16)(raw.x >> 16));
    v[2] = bf2f((u16)(raw.y & 0xffffu)); v[3] = bf2f((u16)(raw.y >> 16));
    v[4] = bf2f((u16)(raw.z & 0xffffu)); v[5] = bf2f((u16)(raw.z >> 16));
    v[6] = bf2f((u16)(raw.w & 0xffffu)); v[7] = bf2f((u16)(raw.w >> 16));
    float mx = v[0];
#pragma unroll
    for (int i = 1; i < 8; i++) mx = fmaxf(mx, v[i]);
#pragma unroll
    for (int off = 32; off; off >>= 1) mx = fmaxf(mx, __shfl_xor(mx, off));
    __shared__ float sm[4];
    __shared__ float sm2[4];
    const int lane = tid & 63, wid = tid >> 6;
    if (lane == 0) sm[wid] = mx;
    __syncthreads();
    mx = fmaxf(fmaxf(sm[0], sm[1]), fmaxf(sm[2], sm[3]));
    float s = 0.f;
#pragma unroll
    for (int i = 0; i < 8; i++) { v[i] = __expf(v[i] - mx); s += v[i]; }
#pragma unroll
    for (int off = 32; off; off >>= 1) s += __shfl_xor(s, off);
    if (lane == 0) sm2[wid] = s;
    __syncthreads();
    s = sm2[0] + sm2[1] + sm2[2] + sm2[3];
    const float inv = 1.0f / s;
    u16 o[8];
#pragma unroll
    for (int i = 0; i < 8; i++) o[i] = f2bf(v[i] * inv);
    *(uint4*)(r + tid * 8) = *(uint4*)o;
}

extern "C" void kernel_launch(void* const* d_in, const int* in_sizes, int n_in,
                              void* d_out, int out_size, void* d_ws, size_t ws_size,
                              hipStream_t stream) {
    const float* target = (const float*)d_in[0];
    const float* src_k  = (const float*)d_in[1];
    const float* src_v  = (const float*)d_in[2];
    const float* Wq = (const float*)d_in[3];
    const float* bq = (const float*)d_in[4];
    const float* Wk = (const float*)d_in[5];
    const float* bk = (const float*)d_in[6];
    const float* Wv = (const float*)d_in[7];
    const float* bv = (const float*)d_in[8];
    const float* g_t = (const float*)d_in[9];
    const float* b_t = (const float*)d_in[10];
    const float* g_k = (const float*)d_in[11];
    const float* b_k = (const float*)d_in[12];
    const float* g_v = (const float*)d_in[13];
    const float* b_v = (const float*)d_in[14];

    // workspace layout (bytes); peak use ~160 MiB
    char* ws = (char*)d_ws;
    u16* q   = (u16*)(ws + 0);            // 16384x1024 bf16  (33.5 MB)
    u16* kk  = (u16*)(ws + 33554432L);    // 16384x1024 bf16
    u16* vT  = (u16*)(ws + 67108864L);    // 8 x 1024 x 2048 bf16
    u16* ln  = (u16*)(ws + 100663296L);   // 16384x1024 bf16 (reused 3x)
    u16* wqb = (u16*)(ws + 134217728L);   // 3 x 1024x1024 bf16
    u16* wkb = wqb + 1048576;
    u16* wvb = wkb + 1048576;
    u16* S   = (u16*)(ws + 100663296L);   // 8x2048x2048 bf16 (aliases ln+W, both dead)

    const float scale = 0.03125f;  // 1024^-0.5

    cast_kernel<<<1024, 256, 0, stream>>>(Wq, wqb);
    cast_kernel<<<1024, 256, 0, stream>>>(Wk, wkb);
    cast_kernel<<<1024, 256, 0, stream>>>(Wv, wvb);

    // Q = LN(target) @ Wq^T + bq
    ln_cast_kernel<<<16384, 256, 0, stream>>>(target, g_t, b_t, ln);
    gemm_bt<0><<<dim3(128, 8, 1), 256, 0, stream>>>(ln, wqb, bq, q,
        16384, 1024, 1024, 1.0f, 0, 0, 0);
    // K = LN(source_k) @ Wk^T + bk
    ln_cast_kernel<<<16384, 256, 0, stream>>>(src_k, g_k, b_k, ln);
    gemm_bt<0><<<dim3(128, 8, 1), 256, 0, stream>>>(ln, wkb, bk, kk,
        16384, 1024, 1024, 1.0f, 0, 0, 0);
    // V = LN(source_v) @ Wv^T + bv, stored transposed per batch: vT[b][d][j]
    ln_cast_kernel<<<16384, 256, 0, stream>>>(src_v, g_v, b_v, ln);
    gemm_bt<1><<<dim3(128, 8, 1), 256, 0, stream>>>(ln, wvb, bv, vT,
        16384, 1024, 1024, 1.0f, 0, 0, 0);

    // S[b] = (q[b] @ k[b]^T) * scale   -> bf16 logits
    gemm_bt<2><<<dim3(16, 16, 8), 256, 0, stream>>>(q, kk, nullptr, S,
        2048, 2048, 1024, scale, 2048L * 1024, 2048L * 1024, 2048L * 2048);

    // softmax rows in-place
    softmax_kernel<<<16384, 256, 0, stream>>>(S);

    // out[b] = P[b] @ vT[b]^T  -> fp32
    gemm_bt<3><<<dim3(16, 8, 8), 256, 0, stream>>>(S, vT, nullptr, d_out,
        2048, 1024, 2048, 1.0f, 2048L * 2048, 1024L * 2048, 2048L * 1024);
}

// Round 4
// 534.494 us; speedup vs baseline: 1.2342x; 1.1280x over previous
//
#include <hip/hip_runtime.h>
#include <cstdint>

using u16 = unsigned short;
using u32 = unsigned int;
typedef __attribute__((ext_vector_type(8))) short short8;
typedef __attribute__((ext_vector_type(4))) float f32x4;

__device__ __forceinline__ float bf2f(u16 u) { return __uint_as_float(((u32)u) << 16); }
__device__ __forceinline__ u16 f2bf(float f) {
    u32 u = __float_as_uint(f);
    u32 r = u + 0x7fffu + ((u >> 16) & 1u);   // round-to-nearest-even
    return (u16)(r >> 16);
}

__device__ __forceinline__ void load_lds16(const void* g, void* l) {
    __builtin_amdgcn_global_load_lds((const __attribute__((address_space(1))) void*)g,
                                     (__attribute__((address_space(3))) void*)l, 16, 0, 0);
}

// ---------------- LayerNorm(row of 1024 fp32) -> bf16 ----------------
__global__ __launch_bounds__(256)
void ln_cast_kernel(const float* __restrict__ x, const float* __restrict__ gw,
                    const float* __restrict__ bw, u16* __restrict__ y) {
    const int row = blockIdx.x;
    const int tid = threadIdx.x;
    const float4 v = ((const float4*)(x + (size_t)row * 1024))[tid];
    float s  = v.x + v.y + v.z + v.w;
    float ss = v.x * v.x + v.y * v.y + v.z * v.z + v.w * v.w;
#pragma unroll
    for (int off = 32; off; off >>= 1) {
        s  += __shfl_xor(s, off);
        ss += __shfl_xor(ss, off);
    }
    __shared__ float sm[8];
    const int lane = tid & 63, wid = tid >> 6;
    if (lane == 0) { sm[wid] = s; sm[wid + 4] = ss; }
    __syncthreads();
    s  = sm[0] + sm[1] + sm[2] + sm[3];
    ss = sm[4] + sm[5] + sm[6] + sm[7];
    const float mu   = s * (1.0f / 1024.0f);
    const float var  = ss * (1.0f / 1024.0f) - mu * mu;
    const float rstd = rsqrtf(var + 1e-5f);
    const float4 g4 = ((const float4*)gw)[tid];
    const float4 b4 = ((const float4*)bw)[tid];
    u16 o[4];
    o[0] = f2bf((v.x - mu) * rstd * g4.x + b4.x);
    o[1] = f2bf((v.y - mu) * rstd * g4.y + b4.y);
    o[2] = f2bf((v.z - mu) * rstd * g4.z + b4.z);
    o[3] = f2bf((v.w - mu) * rstd * g4.w + b4.w);
    *(uint2*)(y + (size_t)row * 1024 + tid * 4) = *(uint2*)o;
}

// ---------------- fp32 -> bf16 cast of the 3 weight matrices ----------------
__global__ __launch_bounds__(256)
void cast3_kernel(const float* __restrict__ wa, const float* __restrict__ wb,
                  const float* __restrict__ wc, u16* __restrict__ oa) {
    const int bid = blockIdx.x;
    const int sel = bid >> 10;
    const float* s = (sel == 0) ? wa : (sel == 1) ? wb : wc;
    u16* d = oa + (size_t)sel * 1048576;
    const int i = (bid & 1023) * 256 + threadIdx.x;
    const float4 v = ((const float4*)s)[i];
    u16 o[4] = { f2bf(v.x), f2bf(v.y), f2bf(v.z), f2bf(v.w) };
    *(uint2*)(d + (size_t)i * 4) = *(uint2*)o;
}

// ---------------- GEMM  C = A(MxK) * B(NxK)^T  (both K-contiguous, bf16 in) -----
// BK=64, 128x128 tile, XOR-swizzled LDS (conflict-free, see r2/r3 notes).
// MODE 0: bf16 out row-major, +bias              (Q/K projection)
// MODE 1: bf16 out transposed per batch, +bias   (V projection -> vT[b][n][m%2048])
// MODE 2: bf16 out = exp(acc*scale), per batch   (dots -> unnormalized P)
// MODE 3: fp32 out = (P@V) / rowsum(P), per batch (PV + fused softmax denom
//         via ones-vector MFMA on the already-loaded A-frags)
template<int MODE>
__global__ __launch_bounds__(256, (MODE == 3 ? 3 : 4))
void gemm_bt(const u16* __restrict__ A, const u16* __restrict__ B,
             const float* __restrict__ bias, void* __restrict__ Cout,
             const int M, const int N, const int K, const float scale,
             const long sA, const long sB, const long sC)
{
    const int bz = blockIdx.z;
    A += (long)bz * sA;
    B += (long)bz * sB;
    __shared__ __align__(16) u16 As[128 * 64];   // 16 KB
    __shared__ __align__(16) u16 Bs[128 * 64];   // 16 KB
    const int tid  = threadIdx.x;
    const int lane = tid & 63, wid = tid >> 6;
    const int wm = (wid & 1) * 64, wn = (wid >> 1) * 64;
    const int m0 = blockIdx.x * 128, n0 = blockIdx.y * 128;

    // staging: round rd covers rows rd*32..rd*32+31; thread t -> row rd*32+(t>>3),
    // fetches global 16B col-group (t&7)^((t>>3)&7)  (swizzle)
    const int scol = (tid & 7) ^ ((tid >> 3) & 7);
    const u16* ap = A + (long)(m0 + (tid >> 3)) * K + scol * 8;
    const u16* bp = B + (long)(n0 + (tid >> 3)) * K + scol * 8;
    u16* asd = As + wid * 512;   // + rd*2048 per round; HW adds lane*16B
    u16* bsd = Bs + wid * 512;
    const long rs32 = 32L * K;

    f32x4 acc[4][4] = {};
    f32x4 acc_l[4] = {};  // MODE 3 only: row sums of A (P) via ones-MFMA
    const short8 ones8 = {16256, 16256, 16256, 16256, 16256, 16256, 16256, 16256}; // bf16 1.0
    const int fr = lane & 15, fq = lane >> 4;

    for (int k0 = 0; k0 < K; k0 += 64) {
#pragma unroll
        for (int rd = 0; rd < 4; rd++) {
            load_lds16(ap + k0 + rd * rs32, asd + rd * 2048);
            load_lds16(bp + k0 + rd * rs32, bsd + rd * 2048);
        }
        __syncthreads();
#pragma unroll
        for (int s = 0; s < 2; s++) {
            short8 af[4], bfv[4];
#pragma unroll
            for (int i = 0; i < 4; i++) {
                const int row = wm + i * 16 + fr;
                af[i] = *(const short8*)&As[row * 64 + (((s * 4 + fq) ^ (row & 7)) * 8)];
            }
#pragma unroll
            for (int j = 0; j < 4; j++) {
                const int row = wn + j * 16 + fr;
                bfv[j] = *(const short8*)&Bs[row * 64 + (((s * 4 + fq) ^ (row & 7)) * 8)];
            }
#pragma unroll
            for (int i = 0; i < 4; i++)
#pragma unroll
                for (int j = 0; j < 4; j++)
                    acc[i][j] = __builtin_amdgcn_mfma_f32_16x16x32_bf16(af[i], bfv[j], acc[i][j], 0, 0, 0);
            if (MODE == 3) {
#pragma unroll
                for (int i = 0; i < 4; i++)
                    acc_l[i] = __builtin_amdgcn_mfma_f32_16x16x32_bf16(af[i], ones8, acc_l[i], 0, 0, 0);
            }
        }
        __syncthreads();
    }

    // epilogue: C/D layout col=lane&15, row=(lane>>4)*4+r
    const int cn = lane & 15;
    const int cm = (lane >> 4) * 4;
    float invl[4][4];
    if (MODE == 3) {
#pragma unroll
        for (int i = 0; i < 4; i++)
#pragma unroll
            for (int r = 0; r < 4; r++) invl[i][r] = 1.0f / acc_l[i][r];
    }
#pragma unroll
    for (int i = 0; i < 4; i++) {
        const int gmb = m0 + wm + i * 16 + cm;
#pragma unroll
        for (int j = 0; j < 4; j++) {
            const int gn = n0 + wn + j * 16 + cn;
            const float bv = (MODE <= 1) ? bias[gn] : 0.0f;
            if (MODE == 1) {
                const int batch = gmb >> 11;
                const int jj = gmb & 2047;
                u16 o[4];
#pragma unroll
                for (int r = 0; r < 4; r++) o[r] = f2bf(acc[i][j][r] + bv);
                *(uint2*)((u16*)Cout + ((long)batch * N + gn) * 2048 + jj) = *(uint2*)o;
            } else {
#pragma unroll
                for (int r = 0; r < 4; r++) {
                    const long gm = gmb + r;
                    float v = acc[i][j][r];
                    if (MODE == 0) v += bv;
                    if (MODE == 2) v = __expf(v * scale);
                    if (MODE == 3)
                        ((float*)Cout)[(long)bz * sC + gm * N + gn] = v * invl[i][r];
                    else if (MODE == 2)
                        ((u16*)Cout)[(long)bz * sC + gm * N + gn] = f2bf(v);
                    else
                        ((u16*)Cout)[gm * (long)N + gn] = f2bf(v);
                }
            }
        }
    }
}

extern "C" void kernel_launch(void* const* d_in, const int* in_sizes, int n_in,
                              void* d_out, int out_size, void* d_ws, size_t ws_size,
                              hipStream_t stream) {
    const float* target = (const float*)d_in[0];
    const float* src_k  = (const float*)d_in[1];
    const float* src_v  = (const float*)d_in[2];
    const float* Wq = (const float*)d_in[3];
    const float* bq = (const float*)d_in[4];
    const float* Wk = (const float*)d_in[5];
    const float* bk = (const float*)d_in[6];
    const float* Wv = (const float*)d_in[7];
    const float* bv = (const float*)d_in[8];
    const float* g_t = (const float*)d_in[9];
    const float* b_t = (const float*)d_in[10];
    const float* g_k = (const float*)d_in[11];
    const float* b_k = (const float*)d_in[12];
    const float* g_v = (const float*)d_in[13];
    const float* b_v = (const float*)d_in[14];

    // workspace layout (bytes); peak use ~160 MiB
    char* ws = (char*)d_ws;
    u16* q   = (u16*)(ws + 0);            // 16384x1024 bf16  (33.5 MB)
    u16* kk  = (u16*)(ws + 33554432L);    // 16384x1024 bf16
    u16* vT  = (u16*)(ws + 67108864L);    // 8 x 1024 x 2048 bf16
    u16* ln  = (u16*)(ws + 100663296L);   // 16384x1024 bf16 (reused 3x)
    u16* wqb = (u16*)(ws + 134217728L);   // 3 x 1024x1024 bf16 (contiguous)
    u16* wkb = wqb + 1048576;
    u16* wvb = wkb + 1048576;
    u16* S   = (u16*)(ws + 100663296L);   // 8x2048x2048 bf16 (aliases ln+W, both dead)

    const float scale = 0.03125f;  // 1024^-0.5

    cast3_kernel<<<3072, 256, 0, stream>>>(Wq, Wk, Wv, wqb);

    // Q = LN(target) @ Wq^T + bq
    ln_cast_kernel<<<16384, 256, 0, stream>>>(target, g_t, b_t, ln);
    gemm_bt<0><<<dim3(128, 8, 1), 256, 0, stream>>>(ln, wqb, bq, q,
        16384, 1024, 1024, 1.0f, 0, 0, 0);
    // K = LN(source_k) @ Wk^T + bk
    ln_cast_kernel<<<16384, 256, 0, stream>>>(src_k, g_k, b_k, ln);
    gemm_bt<0><<<dim3(128, 8, 1), 256, 0, stream>>>(ln, wkb, bk, kk,
        16384, 1024, 1024, 1.0f, 0, 0, 0);
    // V = LN(source_v) @ Wv^T + bv, stored transposed per batch: vT[b][d][j]
    ln_cast_kernel<<<16384, 256, 0, stream>>>(src_v, g_v, b_v, ln);
    gemm_bt<1><<<dim3(128, 8, 1), 256, 0, stream>>>(ln, wvb, bv, vT,
        16384, 1024, 1024, 1.0f, 0, 0, 0);

    // P[b] = exp((q[b] @ k[b]^T) * scale)  -> unnormalized bf16 probs
    gemm_bt<2><<<dim3(16, 16, 8), 256, 0, stream>>>(q, kk, nullptr, S,
        2048, 2048, 1024, scale, 2048L * 1024, 2048L * 1024, 2048L * 2048);

    // out[b] = (P[b] @ vT[b]^T) / rowsum(P[b])  -> fp32 (softmax denom fused)
    gemm_bt<3><<<dim3(16, 8, 8), 256, 0, stream>>>(S, vT, nullptr, d_out,
        2048, 1024, 2048, 1.0f, 2048L * 2048, 1024L * 2048, 2048L * 1024);
}